// Round 1
// baseline (430.743 us; speedup 1.0000x reference)
//
#include <hip/hip_runtime.h>

#define N_NODES 50000
#define E_EDGES 800000
#define IN_F 128
#define HC 128

// ---------------- GEMM: [Q|K|V|SKIP] = x @ [Wq|Wk|Wv|Wskip] + biases -------
// 16 rows per block, 256 threads; thread t computes cols t and t+256 for all
// 16 rows. Weights (4 x 64KB) stay L2-resident.
__global__ __launch_bounds__(256) void gemm_qkvs(
    const float* __restrict__ x,
    const float* __restrict__ Wq, const float* __restrict__ bq,
    const float* __restrict__ Wk, const float* __restrict__ bk,
    const float* __restrict__ Wv, const float* __restrict__ bv,
    const float* __restrict__ Ws, const float* __restrict__ bs,
    float* __restrict__ q, float* __restrict__ k, float* __restrict__ v,
    float* __restrict__ skip)
{
    __shared__ float xs[16][IN_F];
    const int t = threadIdx.x;
    const int row0 = blockIdx.x * 16;

    // stage 16 x-rows (8KB) into LDS, float4 coalesced
    for (int i = t; i < 16 * IN_F / 4; i += 256) {
        int r = i >> 5, c4 = i & 31;
        ((float4*)xs[r])[c4] = ((const float4*)(x + (size_t)(row0 + r) * IN_F))[c4];
    }
    __syncthreads();

    const int cA = t;          // 0..255  -> Wq | Wk
    const int cB = t + 256;    // 256..511-> Wv | Wskip
    const float* WA = (cA < 128) ? Wq : Wk;
    const float* WB = (cB < 384) ? Wv : Ws;
    const float* bA = (cA < 128) ? bq : bk;
    const float* bB = (cB < 384) ? bv : bs;
    const int ca = cA & 127, cb = cB & 127;

    float accA[16], accB[16];
#pragma unroll
    for (int r = 0; r < 16; r++) { accA[r] = 0.f; accB[r] = 0.f; }

    for (int kk = 0; kk < IN_F; kk++) {
        float wa = WA[kk * HC + ca];
        float wb = WB[kk * HC + cb];
#pragma unroll
        for (int r = 0; r < 16; r++) {
            float xv = xs[r][kk];   // LDS broadcast (all threads same addr)
            accA[r] += xv * wa;
            accB[r] += xv * wb;
        }
    }

    float biasA = bA[ca], biasB = bB[cb];
    float* outA = (cA < 128) ? q : k;
    float* outB = (cB < 384) ? v : skip;
#pragma unroll
    for (int r = 0; r < 16; r++) {
        size_t row = row0 + r;
        outA[row * HC + ca] = accA[r] + biasA;
        outB[row * HC + cb] = accB[r] + biasB;
    }
}

// ---------------- CSR build ------------------------------------------------
__global__ __launch_bounds__(256) void hist_k(const int* __restrict__ dst,
                                              int* __restrict__ cnt)
{
    int e = blockIdx.x * 256 + threadIdx.x;
    if (e < E_EDGES) atomicAdd(&cnt[dst[e]], 1);
}

// single-block exclusive scan over cnt[N] -> rowptr[N+1], cursor[N]
__global__ __launch_bounds__(1024) void scan_k(const int* __restrict__ cnt,
                                               int* __restrict__ rowptr,
                                               int* __restrict__ cursor)
{
    __shared__ int sd[1024];
    __shared__ int carry;
    const int t = threadIdx.x;
    if (t == 0) carry = 0;
    __syncthreads();
    for (int base = 0; base < N_NODES; base += 1024) {
        int idx = base + t;
        int val = (idx < N_NODES) ? cnt[idx] : 0;
        sd[t] = val;
        __syncthreads();
        for (int off = 1; off < 1024; off <<= 1) {
            int add = (t >= off) ? sd[t - off] : 0;
            __syncthreads();
            sd[t] += add;
            __syncthreads();
        }
        if (idx < N_NODES) {
            int excl = carry + sd[t] - val;
            rowptr[idx] = excl;
            cursor[idx] = excl;
        }
        __syncthreads();
        if (t == 0) carry += sd[1023];
        __syncthreads();
    }
    if (t == 0) rowptr[N_NODES] = carry;
}

__global__ __launch_bounds__(256) void scatter_k(const int* __restrict__ src,
                                                 const int* __restrict__ dst,
                                                 int* __restrict__ cursor,
                                                 int* __restrict__ ssrc)
{
    int e = blockIdx.x * 256 + threadIdx.x;
    if (e < E_EDGES) {
        int pos = atomicAdd(&cursor[dst[e]], 1);
        ssrc[pos] = src[e];
    }
}

// ---------------- per-node fused attention ---------------------------------
// One 64-lane wave per node. Lane l owns channels 2l,2l+1 (head = l>>4).
// Online softmax without max-subtraction (logits ~ N(0,1), no overflow):
// acc += exp(s)*v[src]; ssum += exp(s); out = acc/ssum + skip; LeakyReLU.
__global__ __launch_bounds__(256) void node_attn(
    const float* __restrict__ q, const float* __restrict__ k,
    const float* __restrict__ v, const int* __restrict__ rowptr,
    const int* __restrict__ ssrc, float* __restrict__ out)
{
    const int wave = (blockIdx.x * 256 + threadIdx.x) >> 6;
    if (wave >= N_NODES) return;
    const int lane = threadIdx.x & 63;
    const int node = wave;

    const float2 myq = *(const float2*)(q + (size_t)node * HC + lane * 2);
    float accx = 0.f, accy = 0.f, ssum = 0.f;
    const int beg = rowptr[node], end = rowptr[node + 1];
    const float scale = 0.17677669529663687f;  // 1/sqrt(32)

    for (int e = beg; e < end; e++) {
        const int j = ssrc[e];
        const float2 kk = *(const float2*)(k + (size_t)j * HC + lane * 2);
        const float2 vv = *(const float2*)(v + (size_t)j * HC + lane * 2);
        float part = myq.x * kk.x + myq.y * kk.y;
        // reduce across the 16 lanes of this head (all lanes get the sum)
        part += __shfl_xor(part, 1);
        part += __shfl_xor(part, 2);
        part += __shfl_xor(part, 4);
        part += __shfl_xor(part, 8);
        const float w = __expf(part * scale);
        accx += w * vv.x;
        accy += w * vv.y;
        ssum += w;
    }

    const float inv = 1.0f / (ssum + 1e-16f);
    const float2 sk = *(const float2*)(out + (size_t)node * HC + lane * 2);
    float ox = accx * inv + sk.x;
    float oy = accy * inv + sk.y;
    ox = ox >= 0.f ? ox : 0.2f * ox;
    oy = oy >= 0.f ? oy : 0.2f * oy;
    *(float2*)(out + (size_t)node * HC + lane * 2) = make_float2(ox, oy);
}

// ---------------- launch ---------------------------------------------------
extern "C" void kernel_launch(void* const* d_in, const int* in_sizes, int n_in,
                              void* d_out, int out_size, void* d_ws, size_t ws_size,
                              hipStream_t stream)
{
    const float* x    = (const float*)d_in[0];
    const int*   ei   = (const int*)d_in[1];   // [2,E] int32: row0=src, row1=dst
    const float* Wq   = (const float*)d_in[2];
    const float* bq   = (const float*)d_in[3];
    const float* Wk   = (const float*)d_in[4];
    const float* bk   = (const float*)d_in[5];
    const float* Wv   = (const float*)d_in[6];
    const float* bv   = (const float*)d_in[7];
    const float* Wsk  = (const float*)d_in[8];
    const float* bsk  = (const float*)d_in[9];
    float* out = (float*)d_out;

    float* ws_f = (float*)d_ws;
    const size_t NF = (size_t)N_NODES * HC;
    float* q = ws_f;
    float* k = ws_f + NF;
    float* v = ws_f + 2 * NF;
    int* ibase  = (int*)(ws_f + 3 * NF);
    int* cnt    = ibase;
    int* rowptr = ibase + N_NODES;
    int* cursor = ibase + 2 * N_NODES + 1;
    int* ssrc   = ibase + 3 * N_NODES + 2;

    const int* srcIdx = ei;
    const int* dstIdx = ei + E_EDGES;

    hipMemsetAsync(cnt, 0, N_NODES * sizeof(int), stream);

    gemm_qkvs<<<N_NODES / 16, 256, 0, stream>>>(x, Wq, bq, Wk, bk, Wv, bv,
                                                Wsk, bsk, q, k, v, out);
    hist_k<<<(E_EDGES + 255) / 256, 256, 0, stream>>>(dstIdx, cnt);
    scan_k<<<1, 1024, 0, stream>>>(cnt, rowptr, cursor);
    scatter_k<<<(E_EDGES + 255) / 256, 256, 0, stream>>>(srcIdx, dstIdx, cursor, ssrc);
    node_attn<<<(N_NODES * 64) / 256, 256, 0, stream>>>(q, k, v, rowptr, ssrc, out);
}

// Round 2
// 335.295 us; speedup vs baseline: 1.2847x; 1.2847x over previous
//
#include <hip/hip_runtime.h>

#define N_NODES 50000
#define E_EDGES 800000
#define IN_F 128
#define HC 128
#define NCOLS 512           // q|k|v|skip concatenated
#define NTILES 32           // NCOLS/16
#define ROWTILES 3125       // N_NODES/16

typedef __attribute__((ext_vector_type(8))) short short8;
typedef __attribute__((ext_vector_type(4))) float floatx4;

__device__ __forceinline__ unsigned short f2bf(float f) {
    union { float f; unsigned u; } x; x.f = f;
    unsigned r = x.u + 0x7FFF + ((x.u >> 16) & 1);
    return (unsigned short)(r >> 16);
}

// ---------------- weight pack: Bpack[nt][ks][lane][8] + bcat[512] ----------
__global__ __launch_bounds__(256) void pack_w(
    const float* __restrict__ Wq, const float* __restrict__ Wk,
    const float* __restrict__ Wv, const float* __restrict__ Ws,
    const float* __restrict__ bq, const float* __restrict__ bk,
    const float* __restrict__ bv, const float* __restrict__ bs,
    short* __restrict__ bpack, float* __restrict__ bcat)
{
    int t = blockIdx.x * 256 + threadIdx.x;    // 0..8191
    int lane = t & 63, ks = (t >> 6) & 3, nt = t >> 8;
    int col = nt * 16 + (lane & 15);
    int sec = col >> 7, c = col & 127;
    const float* W = sec == 0 ? Wq : sec == 1 ? Wk : sec == 2 ? Wv : Ws;
    int kbase = ks * 32 + (lane >> 4) * 8;
    short8 b;
#pragma unroll
    for (int j = 0; j < 8; j++) b[j] = (short)f2bf(W[(size_t)(kbase + j) * HC + c]);
    *(short8*)(bpack + (size_t)t * 8) = b;
    if (t < NCOLS) {
        int s2 = t >> 7, c2 = t & 127;
        bcat[t] = (s2 == 0 ? bq : s2 == 1 ? bk : s2 == 2 ? bv : bs)[c2];
    }
}

// ---------------- fused MFMA GEMM: [q|k|v|skip] = x @ Wcat + bcat ----------
// One wave handles 2 row-tiles (32 rows) x all 512 cols.
__global__ __launch_bounds__(256) void gemm_mfma(
    const float* __restrict__ x, const short* __restrict__ bpack,
    const float* __restrict__ bcat,
    unsigned short* __restrict__ q, unsigned short* __restrict__ k,
    unsigned short* __restrict__ v, float* __restrict__ out)
{
    const int wid = (blockIdx.x * 256 + threadIdx.x) >> 6;
    const int lane = threadIdx.x & 63;
    const int rt0 = wid * 2;
    if (rt0 >= ROWTILES) return;
    const bool has1 = (rt0 + 1) < ROWTILES;
    const int m0 = rt0 * 16 + (lane & 15);
    const int koff = (lane >> 4) * 8;

    short8 a0[4], a1[4];
#pragma unroll
    for (int ks = 0; ks < 4; ks++) {
        const float* p0 = x + (size_t)m0 * IN_F + ks * 32 + koff;
        float4 lo = *(const float4*)p0;
        float4 hi = *(const float4*)(p0 + 4);
        short8 a;
        a[0] = (short)f2bf(lo.x); a[1] = (short)f2bf(lo.y);
        a[2] = (short)f2bf(lo.z); a[3] = (short)f2bf(lo.w);
        a[4] = (short)f2bf(hi.x); a[5] = (short)f2bf(hi.y);
        a[6] = (short)f2bf(hi.z); a[7] = (short)f2bf(hi.w);
        a0[ks] = a;
        if (has1) {
            const float* p1 = p0 + 16 * IN_F;
            float4 lo1 = *(const float4*)p1;
            float4 hi1 = *(const float4*)(p1 + 4);
            short8 b;
            b[0] = (short)f2bf(lo1.x); b[1] = (short)f2bf(lo1.y);
            b[2] = (short)f2bf(lo1.z); b[3] = (short)f2bf(lo1.w);
            b[4] = (short)f2bf(hi1.x); b[5] = (short)f2bf(hi1.y);
            b[6] = (short)f2bf(hi1.z); b[7] = (short)f2bf(hi1.w);
            a1[ks] = b;
        }
    }

    for (int nt = 0; nt < NTILES; nt++) {
        floatx4 acc0 = {0.f, 0.f, 0.f, 0.f}, acc1 = {0.f, 0.f, 0.f, 0.f};
#pragma unroll
        for (int ks = 0; ks < 4; ks++) {
            short8 b = *(const short8*)(bpack + ((size_t)(nt * 4 + ks) * 64 + lane) * 8);
            acc0 = __builtin_amdgcn_mfma_f32_16x16x32_bf16(a0[ks], b, acc0, 0, 0, 0);
            if (has1)
                acc1 = __builtin_amdgcn_mfma_f32_16x16x32_bf16(a1[ks], b, acc1, 0, 0, 0);
        }
        const int col = nt * 16 + (lane & 15);
        const int sec = col >> 7, c = col & 127;
        const float bias = bcat[col];
        const int rb0 = rt0 * 16 + (lane >> 4) * 4;
#pragma unroll
        for (int r = 0; r < 4; r++) {
            float val = acc0[r] + bias;
            size_t off = (size_t)(rb0 + r) * HC + c;
            if (sec == 0)      q[off] = f2bf(val);
            else if (sec == 1) k[off] = f2bf(val);
            else if (sec == 2) v[off] = f2bf(val);
            else               out[off] = val;
        }
        if (has1) {
            const int rb1 = rb0 + 16;
#pragma unroll
            for (int r = 0; r < 4; r++) {
                float val = acc1[r] + bias;
                size_t off = (size_t)(rb1 + r) * HC + c;
                if (sec == 0)      q[off] = f2bf(val);
                else if (sec == 1) k[off] = f2bf(val);
                else if (sec == 2) v[off] = f2bf(val);
                else               out[off] = val;
            }
        }
    }
}

// ---------------- CSR build ------------------------------------------------
__global__ __launch_bounds__(256) void hist_k(const int* __restrict__ dst,
                                              int* __restrict__ cnt)
{
    int e = blockIdx.x * 256 + threadIdx.x;
    if (e < E_EDGES) atomicAdd(&cnt[dst[e]], 1);
}

// single block, 1024 threads; thread t owns 49 contiguous counters
__global__ __launch_bounds__(1024) void scan_k(const int* __restrict__ cnt,
                                               int* __restrict__ rowptr,
                                               int* __restrict__ cursor)
{
    __shared__ int wsum[16];
    const int t = threadIdx.x;
    const int lane = t & 63, w = t >> 6;
    const int CHUNK = 49;
    const int base = t * CHUNK;

    int total = 0;
    for (int i = 0; i < CHUNK; i++) {
        int idx = base + i;
        if (idx < N_NODES) total += cnt[idx];
    }
    // inclusive wave scan
    int incl = total;
    for (int off = 1; off < 64; off <<= 1) {
        int u = __shfl_up(incl, off);
        if (lane >= off) incl += u;
    }
    if (lane == 63) wsum[w] = incl;
    __syncthreads();
    if (t == 0) {
        int run = 0;
        for (int i = 0; i < 16; i++) { int tmp = wsum[i]; wsum[i] = run; run += tmp; }
    }
    __syncthreads();
    int excl = wsum[w] + incl - total;
    int run = excl;
    for (int i = 0; i < CHUNK; i++) {
        int idx = base + i;
        if (idx < N_NODES) {
            int c = cnt[idx];
            rowptr[idx] = run;
            cursor[idx] = run;
            run += c;
        }
    }
    if (t == 0) rowptr[N_NODES] = E_EDGES;
}

__global__ __launch_bounds__(256) void scatter_k(const int* __restrict__ src,
                                                 const int* __restrict__ dst,
                                                 int* __restrict__ cursor,
                                                 int* __restrict__ ssrc)
{
    int e = blockIdx.x * 256 + threadIdx.x;
    if (e < E_EDGES) {
        int pos = atomicAdd(&cursor[dst[e]], 1);
        ssrc[pos] = src[e];
    }
}

// ---------------- per-node fused attention (bf16 gather) -------------------
__global__ __launch_bounds__(256) void node_attn(
    const unsigned short* __restrict__ q, const unsigned short* __restrict__ k,
    const unsigned short* __restrict__ v, const int* __restrict__ rowptr,
    const int* __restrict__ ssrc, float* __restrict__ out)
{
    const int wave = (blockIdx.x * 256 + threadIdx.x) >> 6;
    if (wave >= N_NODES) return;
    const int lane = threadIdx.x & 63;
    const int node = wave;

    union { unsigned u; float f; } cv;
    const unsigned uq = *(const unsigned*)(q + (size_t)node * HC + lane * 2);
    cv.u = uq << 16;          float qx = cv.f;
    cv.u = uq & 0xFFFF0000u;  float qy = cv.f;

    float accx = 0.f, accy = 0.f, ssum = 0.f;
    const int beg = rowptr[node], end = rowptr[node + 1];
    const float scale = 0.17677669529663687f;  // 1/sqrt(32)

    int e = beg;
    for (; e + 1 < end; e += 2) {
        const int j0 = ssrc[e], j1 = ssrc[e + 1];
        const unsigned uk0 = *(const unsigned*)(k + (size_t)j0 * HC + lane * 2);
        const unsigned uv0 = *(const unsigned*)(v + (size_t)j0 * HC + lane * 2);
        const unsigned uk1 = *(const unsigned*)(k + (size_t)j1 * HC + lane * 2);
        const unsigned uv1 = *(const unsigned*)(v + (size_t)j1 * HC + lane * 2);
        cv.u = uk0 << 16;         float k0x = cv.f;
        cv.u = uk0 & 0xFFFF0000u; float k0y = cv.f;
        cv.u = uk1 << 16;         float k1x = cv.f;
        cv.u = uk1 & 0xFFFF0000u; float k1y = cv.f;
        float p0 = qx * k0x + qy * k0y;
        float p1 = qx * k1x + qy * k1y;
        p0 += __shfl_xor(p0, 1);  p1 += __shfl_xor(p1, 1);
        p0 += __shfl_xor(p0, 2);  p1 += __shfl_xor(p1, 2);
        p0 += __shfl_xor(p0, 4);  p1 += __shfl_xor(p1, 4);
        p0 += __shfl_xor(p0, 8);  p1 += __shfl_xor(p1, 8);
        const float w0 = __expf(p0 * scale);
        const float w1 = __expf(p1 * scale);
        cv.u = uv0 << 16;         float v0x = cv.f;
        cv.u = uv0 & 0xFFFF0000u; float v0y = cv.f;
        cv.u = uv1 << 16;         float v1x = cv.f;
        cv.u = uv1 & 0xFFFF0000u; float v1y = cv.f;
        accx += w0 * v0x + w1 * v1x;
        accy += w0 * v0y + w1 * v1y;
        ssum += w0 + w1;
    }
    if (e < end) {
        const int j0 = ssrc[e];
        const unsigned uk0 = *(const unsigned*)(k + (size_t)j0 * HC + lane * 2);
        const unsigned uv0 = *(const unsigned*)(v + (size_t)j0 * HC + lane * 2);
        cv.u = uk0 << 16;         float k0x = cv.f;
        cv.u = uk0 & 0xFFFF0000u; float k0y = cv.f;
        float p0 = qx * k0x + qy * k0y;
        p0 += __shfl_xor(p0, 1);
        p0 += __shfl_xor(p0, 2);
        p0 += __shfl_xor(p0, 4);
        p0 += __shfl_xor(p0, 8);
        const float w0 = __expf(p0 * scale);
        cv.u = uv0 << 16;         float v0x = cv.f;
        cv.u = uv0 & 0xFFFF0000u; float v0y = cv.f;
        accx += w0 * v0x;
        accy += w0 * v0y;
        ssum += w0;
    }

    const float inv = 1.0f / (ssum + 1e-16f);
    const float2 sk = *(const float2*)(out + (size_t)node * HC + lane * 2);
    float ox = accx * inv + sk.x;
    float oy = accy * inv + sk.y;
    ox = ox >= 0.f ? ox : 0.2f * ox;
    oy = oy >= 0.f ? oy : 0.2f * oy;
    *(float2*)(out + (size_t)node * HC + lane * 2) = make_float2(ox, oy);
}

// ---------------- launch ---------------------------------------------------
extern "C" void kernel_launch(void* const* d_in, const int* in_sizes, int n_in,
                              void* d_out, int out_size, void* d_ws, size_t ws_size,
                              hipStream_t stream)
{
    const float* x    = (const float*)d_in[0];
    const int*   ei   = (const int*)d_in[1];
    const float* Wq   = (const float*)d_in[2];
    const float* bq   = (const float*)d_in[3];
    const float* Wk   = (const float*)d_in[4];
    const float* bk   = (const float*)d_in[5];
    const float* Wv   = (const float*)d_in[6];
    const float* bv   = (const float*)d_in[7];
    const float* Wsk  = (const float*)d_in[8];
    const float* bsk  = (const float*)d_in[9];
    float* out = (float*)d_out;

    char* w = (char*)d_ws;
    const size_t NFB = (size_t)N_NODES * HC * sizeof(unsigned short); // 12.8MB
    unsigned short* q = (unsigned short*)w;            w += NFB;
    unsigned short* k = (unsigned short*)w;            w += NFB;
    unsigned short* v = (unsigned short*)w;            w += NFB;
    short* bpack = (short*)w;                          w += 8192 * 8 * sizeof(short);
    float* bcat  = (float*)w;                          w += NCOLS * sizeof(float);
    int* cnt    = (int*)w;                             w += N_NODES * sizeof(int);
    int* rowptr = (int*)w;                             w += (N_NODES + 1) * sizeof(int);
    int* cursor = (int*)w;                             w += N_NODES * sizeof(int);
    int* ssrc   = (int*)w;

    const int* srcIdx = ei;
    const int* dstIdx = ei + E_EDGES;

    hipMemsetAsync(cnt, 0, N_NODES * sizeof(int), stream);

    pack_w<<<32, 256, 0, stream>>>(Wq, Wk, Wv, Wsk, bq, bk, bv, bsk, bpack, bcat);
    hist_k<<<(E_EDGES + 255) / 256, 256, 0, stream>>>(dstIdx, cnt);
    gemm_mfma<<<391, 256, 0, stream>>>(x, bpack, bcat, q, k, v, out);
    scan_k<<<1, 1024, 0, stream>>>(cnt, rowptr, cursor);
    scatter_k<<<(E_EDGES + 255) / 256, 256, 0, stream>>>(srcIdx, dstIdx, cursor, ssrc);
    node_attn<<<(N_NODES * 64) / 256, 256, 0, stream>>>(q, k, v, rowptr, ssrc, out);
}

// Round 3
// 218.708 us; speedup vs baseline: 1.9695x; 1.5331x over previous
//
#include <hip/hip_runtime.h>

#define N_NODES 50000
#define E_EDGES 800000
#define IN_F 128
#define HC 128
#define NCOLS 512           // q|k|v|skip concatenated
#define NTILES 32           // NCOLS/16
#define ROWTILES 3125       // N_NODES/16
#define SCAN_BLOCKS 196     // ceil(50000/256)

typedef __attribute__((ext_vector_type(8))) short short8;
typedef __attribute__((ext_vector_type(4))) float floatx4;

__device__ __forceinline__ unsigned short f2bf(float f) {
    union { float f; unsigned u; } x; x.f = f;
    unsigned r = x.u + 0x7FFF + ((x.u >> 16) & 1);
    return (unsigned short)(r >> 16);
}

// ---------------- weight pack: Bpack[nt][ks][lane][8] + bcat[512] ----------
__global__ __launch_bounds__(256) void pack_w(
    const float* __restrict__ Wq, const float* __restrict__ Wk,
    const float* __restrict__ Wv, const float* __restrict__ Ws,
    const float* __restrict__ bq, const float* __restrict__ bk,
    const float* __restrict__ bv, const float* __restrict__ bs,
    short* __restrict__ bpack, float* __restrict__ bcat)
{
    int t = blockIdx.x * 256 + threadIdx.x;    // 0..8191
    int lane = t & 63, ks = (t >> 6) & 3, nt = t >> 8;
    int col = nt * 16 + (lane & 15);
    int sec = col >> 7, c = col & 127;
    const float* W = sec == 0 ? Wq : sec == 1 ? Wk : sec == 2 ? Wv : Ws;
    int kbase = ks * 32 + (lane >> 4) * 8;
    short8 b;
#pragma unroll
    for (int j = 0; j < 8; j++) b[j] = (short)f2bf(W[(size_t)(kbase + j) * HC + c]);
    *(short8*)(bpack + (size_t)t * 8) = b;
    if (t < NCOLS) {
        int s2 = t >> 7, c2 = t & 127;
        bcat[t] = (s2 == 0 ? bq : s2 == 1 ? bk : s2 == 2 ? bv : bs)[c2];
    }
}

// ---------------- fused MFMA GEMM: [q|k|v|skip] = x @ Wcat + bcat ----------
__global__ __launch_bounds__(256) void gemm_mfma(
    const float* __restrict__ x, const short* __restrict__ bpack,
    const float* __restrict__ bcat,
    unsigned short* __restrict__ q, unsigned short* __restrict__ k,
    unsigned short* __restrict__ v, float* __restrict__ out)
{
    const int wid = (blockIdx.x * 256 + threadIdx.x) >> 6;
    const int lane = threadIdx.x & 63;
    const int rt0 = wid * 2;
    if (rt0 >= ROWTILES) return;
    const bool has1 = (rt0 + 1) < ROWTILES;
    const int m0 = rt0 * 16 + (lane & 15);
    const int koff = (lane >> 4) * 8;

    short8 a0[4], a1[4];
#pragma unroll
    for (int ks = 0; ks < 4; ks++) {
        const float* p0 = x + (size_t)m0 * IN_F + ks * 32 + koff;
        float4 lo = *(const float4*)p0;
        float4 hi = *(const float4*)(p0 + 4);
        short8 a;
        a[0] = (short)f2bf(lo.x); a[1] = (short)f2bf(lo.y);
        a[2] = (short)f2bf(lo.z); a[3] = (short)f2bf(lo.w);
        a[4] = (short)f2bf(hi.x); a[5] = (short)f2bf(hi.y);
        a[6] = (short)f2bf(hi.z); a[7] = (short)f2bf(hi.w);
        a0[ks] = a;
        if (has1) {
            const float* p1 = p0 + 16 * IN_F;
            float4 lo1 = *(const float4*)p1;
            float4 hi1 = *(const float4*)(p1 + 4);
            short8 b;
            b[0] = (short)f2bf(lo1.x); b[1] = (short)f2bf(lo1.y);
            b[2] = (short)f2bf(lo1.z); b[3] = (short)f2bf(lo1.w);
            b[4] = (short)f2bf(hi1.x); b[5] = (short)f2bf(hi1.y);
            b[6] = (short)f2bf(hi1.z); b[7] = (short)f2bf(hi1.w);
            a1[ks] = b;
        }
    }

    for (int nt = 0; nt < NTILES; nt++) {
        floatx4 acc0 = {0.f, 0.f, 0.f, 0.f}, acc1 = {0.f, 0.f, 0.f, 0.f};
#pragma unroll
        for (int ks = 0; ks < 4; ks++) {
            short8 b = *(const short8*)(bpack + ((size_t)(nt * 4 + ks) * 64 + lane) * 8);
            acc0 = __builtin_amdgcn_mfma_f32_16x16x32_bf16(a0[ks], b, acc0, 0, 0, 0);
            if (has1)
                acc1 = __builtin_amdgcn_mfma_f32_16x16x32_bf16(a1[ks], b, acc1, 0, 0, 0);
        }
        const int col = nt * 16 + (lane & 15);
        const int sec = col >> 7, c = col & 127;
        const float bias = bcat[col];
        const int rb0 = rt0 * 16 + (lane >> 4) * 4;
#pragma unroll
        for (int r = 0; r < 4; r++) {
            float val = acc0[r] + bias;
            size_t off = (size_t)(rb0 + r) * HC + c;
            if (sec == 0)      q[off] = f2bf(val);
            else if (sec == 1) k[off] = f2bf(val);
            else if (sec == 2) v[off] = f2bf(val);
            else               out[off] = val;
        }
        if (has1) {
            const int rb1 = rb0 + 16;
#pragma unroll
            for (int r = 0; r < 4; r++) {
                float val = acc1[r] + bias;
                size_t off = (size_t)(rb1 + r) * HC + c;
                if (sec == 0)      q[off] = f2bf(val);
                else if (sec == 1) k[off] = f2bf(val);
                else if (sec == 2) v[off] = f2bf(val);
                else               out[off] = val;
            }
        }
    }
}

// ---------------- CSR build ------------------------------------------------
__global__ __launch_bounds__(256) void hist_k(const int* __restrict__ dst,
                                              int* __restrict__ cnt)
{
    int e = blockIdx.x * 256 + threadIdx.x;
    if (e < E_EDGES) atomicAdd(&cnt[dst[e]], 1);
}

// block-level inclusive scan helper (256 threads, 4 waves)
__device__ __forceinline__ int block_incl_scan(int val, int t, int* wsum) {
    const int lane = t & 63, w = t >> 6;
    int incl = val;
#pragma unroll
    for (int off = 1; off < 64; off <<= 1) {
        int u = __shfl_up(incl, off);
        if (lane >= off) incl += u;
    }
    if (lane == 63) wsum[w] = incl;
    __syncthreads();
    int pre = 0;
#pragma unroll
    for (int i = 0; i < 4; i++) if (i < w) pre += wsum[i];
    return incl + pre;
}

// k1: per-block sums of cnt
__global__ __launch_bounds__(256) void bsum_k(const int* __restrict__ cnt,
                                              int* __restrict__ bsum)
{
    __shared__ int wsum[4];
    int idx = blockIdx.x * 256 + threadIdx.x;
    int val = (idx < N_NODES) ? cnt[idx] : 0;
    const int lane = threadIdx.x & 63, w = threadIdx.x >> 6;
    int s = val;
#pragma unroll
    for (int off = 32; off >= 1; off >>= 1) s += __shfl_xor(s, off);
    if (lane == 0) wsum[w] = s;
    __syncthreads();
    if (threadIdx.x == 0)
        bsum[blockIdx.x] = wsum[0] + wsum[1] + wsum[2] + wsum[3];
}

// k2: single-block exclusive scan of bsum[196] -> boff[196]
__global__ __launch_bounds__(256) void bscan_k(const int* __restrict__ bsum,
                                               int* __restrict__ boff)
{
    __shared__ int wsum[4];
    const int t = threadIdx.x;
    int val = (t < SCAN_BLOCKS) ? bsum[t] : 0;
    int incl = block_incl_scan(val, t, wsum);
    if (t < SCAN_BLOCKS) boff[t] = incl - val;
}

// k3: per-block scan + global offset -> rowptr, cursor
__global__ __launch_bounds__(256) void bapply_k(const int* __restrict__ cnt,
                                                const int* __restrict__ boff,
                                                int* __restrict__ rowptr,
                                                int* __restrict__ cursor)
{
    __shared__ int wsum[4];
    int idx = blockIdx.x * 256 + threadIdx.x;
    int val = (idx < N_NODES) ? cnt[idx] : 0;
    int incl = block_incl_scan(val, threadIdx.x, wsum);
    int excl = boff[blockIdx.x] + incl - val;
    if (idx < N_NODES) { rowptr[idx] = excl; cursor[idx] = excl; }
    if (idx == N_NODES - 1) rowptr[N_NODES] = E_EDGES;
}

__global__ __launch_bounds__(256) void scatter_k(const int* __restrict__ src,
                                                 const int* __restrict__ dst,
                                                 int* __restrict__ cursor,
                                                 int* __restrict__ ssrc)
{
    int e = blockIdx.x * 256 + threadIdx.x;
    if (e < E_EDGES) {
        int pos = atomicAdd(&cursor[dst[e]], 1);
        ssrc[pos] = src[e];
    }
}

// ---------------- per-node fused attention (bf16 gather) -------------------
__global__ __launch_bounds__(256) void node_attn(
    const unsigned short* __restrict__ q, const unsigned short* __restrict__ k,
    const unsigned short* __restrict__ v, const int* __restrict__ rowptr,
    const int* __restrict__ ssrc, float* __restrict__ out)
{
    const int wave = (blockIdx.x * 256 + threadIdx.x) >> 6;
    if (wave >= N_NODES) return;
    const int lane = threadIdx.x & 63;
    const int node = wave;

    union { unsigned u; float f; } cv;
    const unsigned uq = *(const unsigned*)(q + (size_t)node * HC + lane * 2);
    cv.u = uq << 16;          float qx = cv.f;
    cv.u = uq & 0xFFFF0000u;  float qy = cv.f;

    float accx = 0.f, accy = 0.f, ssum = 0.f;
    const int beg = rowptr[node], end = rowptr[node + 1];
    const float scale = 0.17677669529663687f;  // 1/sqrt(32)

    int e = beg;
    for (; e + 1 < end; e += 2) {
        const int j0 = ssrc[e], j1 = ssrc[e + 1];
        const unsigned uk0 = *(const unsigned*)(k + (size_t)j0 * HC + lane * 2);
        const unsigned uv0 = *(const unsigned*)(v + (size_t)j0 * HC + lane * 2);
        const unsigned uk1 = *(const unsigned*)(k + (size_t)j1 * HC + lane * 2);
        const unsigned uv1 = *(const unsigned*)(v + (size_t)j1 * HC + lane * 2);
        cv.u = uk0 << 16;         float k0x = cv.f;
        cv.u = uk0 & 0xFFFF0000u; float k0y = cv.f;
        cv.u = uk1 << 16;         float k1x = cv.f;
        cv.u = uk1 & 0xFFFF0000u; float k1y = cv.f;
        float p0 = qx * k0x + qy * k0y;
        float p1 = qx * k1x + qy * k1y;
        p0 += __shfl_xor(p0, 1);  p1 += __shfl_xor(p1, 1);
        p0 += __shfl_xor(p0, 2);  p1 += __shfl_xor(p1, 2);
        p0 += __shfl_xor(p0, 4);  p1 += __shfl_xor(p1, 4);
        p0 += __shfl_xor(p0, 8);  p1 += __shfl_xor(p1, 8);
        const float w0 = __expf(p0 * scale);
        const float w1 = __expf(p1 * scale);
        cv.u = uv0 << 16;         float v0x = cv.f;
        cv.u = uv0 & 0xFFFF0000u; float v0y = cv.f;
        cv.u = uv1 << 16;         float v1x = cv.f;
        cv.u = uv1 & 0xFFFF0000u; float v1y = cv.f;
        accx += w0 * v0x + w1 * v1x;
        accy += w0 * v0y + w1 * v1y;
        ssum += w0 + w1;
    }
    if (e < end) {
        const int j0 = ssrc[e];
        const unsigned uk0 = *(const unsigned*)(k + (size_t)j0 * HC + lane * 2);
        const unsigned uv0 = *(const unsigned*)(v + (size_t)j0 * HC + lane * 2);
        cv.u = uk0 << 16;         float k0x = cv.f;
        cv.u = uk0 & 0xFFFF0000u; float k0y = cv.f;
        float p0 = qx * k0x + qy * k0y;
        p0 += __shfl_xor(p0, 1);
        p0 += __shfl_xor(p0, 2);
        p0 += __shfl_xor(p0, 4);
        p0 += __shfl_xor(p0, 8);
        const float w0 = __expf(p0 * scale);
        cv.u = uv0 << 16;         float v0x = cv.f;
        cv.u = uv0 & 0xFFFF0000u; float v0y = cv.f;
        accx += w0 * v0x;
        accy += w0 * v0y;
        ssum += w0;
    }

    const float inv = 1.0f / (ssum + 1e-16f);
    const float2 sk = *(const float2*)(out + (size_t)node * HC + lane * 2);
    float ox = accx * inv + sk.x;
    float oy = accy * inv + sk.y;
    ox = ox >= 0.f ? ox : 0.2f * ox;
    oy = oy >= 0.f ? oy : 0.2f * oy;
    *(float2*)(out + (size_t)node * HC + lane * 2) = make_float2(ox, oy);
}

// ---------------- launch ---------------------------------------------------
extern "C" void kernel_launch(void* const* d_in, const int* in_sizes, int n_in,
                              void* d_out, int out_size, void* d_ws, size_t ws_size,
                              hipStream_t stream)
{
    const float* x    = (const float*)d_in[0];
    const int*   ei   = (const int*)d_in[1];
    const float* Wq   = (const float*)d_in[2];
    const float* bq   = (const float*)d_in[3];
    const float* Wk   = (const float*)d_in[4];
    const float* bk   = (const float*)d_in[5];
    const float* Wv   = (const float*)d_in[6];
    const float* bv   = (const float*)d_in[7];
    const float* Wsk  = (const float*)d_in[8];
    const float* bsk  = (const float*)d_in[9];
    float* out = (float*)d_out;

    char* w = (char*)d_ws;
    const size_t NFB = (size_t)N_NODES * HC * sizeof(unsigned short); // 12.8MB
    unsigned short* q = (unsigned short*)w;            w += NFB;
    unsigned short* k = (unsigned short*)w;            w += NFB;
    unsigned short* v = (unsigned short*)w;            w += NFB;
    short* bpack = (short*)w;                          w += 8192 * 8 * sizeof(short);
    float* bcat  = (float*)w;                          w += NCOLS * sizeof(float);
    int* cnt    = (int*)w;                             w += N_NODES * sizeof(int);
    int* rowptr = (int*)w;                             w += (N_NODES + 1) * sizeof(int);
    int* cursor = (int*)w;                             w += N_NODES * sizeof(int);
    int* bsum   = (int*)w;                             w += SCAN_BLOCKS * sizeof(int);
    int* boff   = (int*)w;                             w += SCAN_BLOCKS * sizeof(int);
    int* ssrc   = (int*)w;

    const int* srcIdx = ei;
    const int* dstIdx = ei + E_EDGES;

    hipMemsetAsync(cnt, 0, N_NODES * sizeof(int), stream);

    pack_w<<<32, 256, 0, stream>>>(Wq, Wk, Wv, Wsk, bq, bk, bv, bsk, bpack, bcat);
    hist_k<<<(E_EDGES + 255) / 256, 256, 0, stream>>>(dstIdx, cnt);
    gemm_mfma<<<391, 256, 0, stream>>>(x, bpack, bcat, q, k, v, out);
    bsum_k<<<SCAN_BLOCKS, 256, 0, stream>>>(cnt, bsum);
    bscan_k<<<1, 256, 0, stream>>>(bsum, boff);
    bapply_k<<<SCAN_BLOCKS, 256, 0, stream>>>(cnt, boff, rowptr, cursor);
    scatter_k<<<(E_EDGES + 255) / 256, 256, 0, stream>>>(srcIdx, dstIdx, cursor, ssrc);
    node_attn<<<(N_NODES * 64) / 256, 256, 0, stream>>>(q, k, v, rowptr, ssrc, out);
}

// Round 4
// 160.959 us; speedup vs baseline: 2.6761x; 1.3588x over previous
//
#include <hip/hip_runtime.h>

#define N_NODES 50000
#define E_EDGES 800000
#define IN_F 128
#define HC 128
#define NCOLS 512           // q|k|v|skip concatenated
#define ROWTILES 3125       // N_NODES/16
#define SCAN_BLOCKS 196     // ceil(50000/256)

typedef __attribute__((ext_vector_type(8))) short short8;
typedef __attribute__((ext_vector_type(4))) float floatx4;

__device__ __forceinline__ unsigned short f2bf(float f) {
    union { float f; unsigned u; } x; x.f = f;
    unsigned r = x.u + 0x7FFF + ((x.u >> 16) & 1);
    return (unsigned short)(r >> 16);
}

// ---------------- weight pack: Bpack[nt][ks][lane][8] + bcat[512] ----------
__global__ __launch_bounds__(256) void pack_w(
    const float* __restrict__ Wq, const float* __restrict__ Wk,
    const float* __restrict__ Wv, const float* __restrict__ Ws,
    const float* __restrict__ bq, const float* __restrict__ bk,
    const float* __restrict__ bv, const float* __restrict__ bs,
    short* __restrict__ bpack, float* __restrict__ bcat)
{
    int t = blockIdx.x * 256 + threadIdx.x;    // 0..8191
    int lane = t & 63, ks = (t >> 6) & 3, nt = t >> 8;
    int col = nt * 16 + (lane & 15);
    int sec = col >> 7, c = col & 127;
    const float* W = sec == 0 ? Wq : sec == 1 ? Wk : sec == 2 ? Wv : Ws;
    int kbase = ks * 32 + (lane >> 4) * 8;
    short8 b;
#pragma unroll
    for (int j = 0; j < 8; j++) b[j] = (short)f2bf(W[(size_t)(kbase + j) * HC + c]);
    *(short8*)(bpack + (size_t)t * 8) = b;
    if (t < NCOLS) {
        int s2 = t >> 7, c2 = t & 127;
        bcat[t] = (s2 == 0 ? bq : s2 == 1 ? bk : s2 == 2 ? bv : bs)[c2];
    }
}

// ---------------- fused MFMA GEMM ------------------------------------------
// Block = 1 row-tile (16 rows), 4 waves; wave cg owns 128 cols (sec==cg).
// 3125 blocks -> 12500 waves, ~12 waves/SIMD.
__global__ __launch_bounds__(256) void gemm_mfma(
    const float* __restrict__ x, const short* __restrict__ bpack,
    const float* __restrict__ bcat,
    unsigned short* __restrict__ q, unsigned short* __restrict__ k,
    unsigned short* __restrict__ v, float* __restrict__ out)
{
    const int rt = blockIdx.x;
    const int cg = threadIdx.x >> 6;        // 0:q 1:k 2:v 3:skip
    const int lane = threadIdx.x & 63;
    const int m0 = rt * 16 + (lane & 15);
    const int koff = (lane >> 4) * 8;

    short8 a0[4];
#pragma unroll
    for (int ks = 0; ks < 4; ks++) {
        const float* p0 = x + (size_t)m0 * IN_F + ks * 32 + koff;
        float4 lo = *(const float4*)p0;
        float4 hi = *(const float4*)(p0 + 4);
        short8 a;
        a[0] = (short)f2bf(lo.x); a[1] = (short)f2bf(lo.y);
        a[2] = (short)f2bf(lo.z); a[3] = (short)f2bf(lo.w);
        a[4] = (short)f2bf(hi.x); a[5] = (short)f2bf(hi.y);
        a[6] = (short)f2bf(hi.z); a[7] = (short)f2bf(hi.w);
        a0[ks] = a;
    }

    unsigned short* dstb = (cg == 0) ? q : (cg == 1) ? k : v;  // bf16 sections
    const int rb0 = rt * 16 + (lane >> 4) * 4;

#pragma unroll
    for (int nt8 = 0; nt8 < 8; nt8++) {
        const int nt = cg * 8 + nt8;
        floatx4 acc = {0.f, 0.f, 0.f, 0.f};
#pragma unroll
        for (int ks = 0; ks < 4; ks++) {
            short8 b = *(const short8*)(bpack + ((size_t)(nt * 4 + ks) * 64 + lane) * 8);
            acc = __builtin_amdgcn_mfma_f32_16x16x32_bf16(a0[ks], b, acc, 0, 0, 0);
        }
        const int c = nt8 * 16 + (lane & 15);       // 0..127 within section
        const float bias = bcat[cg * 128 + c];
        if (cg < 3) {
#pragma unroll
            for (int r = 0; r < 4; r++)
                dstb[(size_t)(rb0 + r) * HC + c] = f2bf(acc[r] + bias);
        } else {
#pragma unroll
            for (int r = 0; r < 4; r++)
                out[(size_t)(rb0 + r) * HC + c] = acc[r] + bias;
        }
    }
}

// ---------------- CSR build ------------------------------------------------
// hist also records each edge's rank within its dst bucket -> atomic-free scatter
__global__ __launch_bounds__(256) void hist_k(const int* __restrict__ dst,
                                              int* __restrict__ cnt,
                                              int* __restrict__ rank)
{
    int e = blockIdx.x * 256 + threadIdx.x;
    if (e < E_EDGES) rank[e] = atomicAdd(&cnt[dst[e]], 1);
}

__device__ __forceinline__ int block_incl_scan(int val, int t, int* wsum) {
    const int lane = t & 63, w = t >> 6;
    int incl = val;
#pragma unroll
    for (int off = 1; off < 64; off <<= 1) {
        int u = __shfl_up(incl, off);
        if (lane >= off) incl += u;
    }
    if (lane == 63) wsum[w] = incl;
    __syncthreads();
    int pre = 0;
#pragma unroll
    for (int i = 0; i < 4; i++) if (i < w) pre += wsum[i];
    return incl + pre;
}

__global__ __launch_bounds__(256) void bsum_k(const int* __restrict__ cnt,
                                              int* __restrict__ bsum)
{
    __shared__ int wsum[4];
    int idx = blockIdx.x * 256 + threadIdx.x;
    int val = (idx < N_NODES) ? cnt[idx] : 0;
    const int lane = threadIdx.x & 63, w = threadIdx.x >> 6;
    int s = val;
#pragma unroll
    for (int off = 32; off >= 1; off >>= 1) s += __shfl_xor(s, off);
    if (lane == 0) wsum[w] = s;
    __syncthreads();
    if (threadIdx.x == 0)
        bsum[blockIdx.x] = wsum[0] + wsum[1] + wsum[2] + wsum[3];
}

__global__ __launch_bounds__(256) void bscan_k(const int* __restrict__ bsum,
                                               int* __restrict__ boff)
{
    __shared__ int wsum[4];
    const int t = threadIdx.x;
    int val = (t < SCAN_BLOCKS) ? bsum[t] : 0;
    int incl = block_incl_scan(val, t, wsum);
    if (t < SCAN_BLOCKS) boff[t] = incl - val;
}

__global__ __launch_bounds__(256) void bapply_k(const int* __restrict__ cnt,
                                                const int* __restrict__ boff,
                                                int* __restrict__ rowptr)
{
    __shared__ int wsum[4];
    int idx = blockIdx.x * 256 + threadIdx.x;
    int val = (idx < N_NODES) ? cnt[idx] : 0;
    int incl = block_incl_scan(val, threadIdx.x, wsum);
    int excl = boff[blockIdx.x] + incl - val;
    if (idx < N_NODES) rowptr[idx] = excl;
    if (idx == N_NODES - 1) rowptr[N_NODES] = E_EDGES;
}

__global__ __launch_bounds__(256) void scatter_k(const int* __restrict__ src,
                                                 const int* __restrict__ dst,
                                                 const int* __restrict__ rowptr,
                                                 const int* __restrict__ rank,
                                                 int* __restrict__ ssrc)
{
    int e = blockIdx.x * 256 + threadIdx.x;
    if (e < E_EDGES) ssrc[rowptr[dst[e]] + rank[e]] = src[e];
}

// ---------------- per-node fused attention (bf16 gather, unroll 4) ---------
__global__ __launch_bounds__(256) void node_attn(
    const unsigned short* __restrict__ q, const unsigned short* __restrict__ k,
    const unsigned short* __restrict__ v, const int* __restrict__ rowptr,
    const int* __restrict__ ssrc, float* __restrict__ out)
{
    const int wave = (blockIdx.x * 256 + threadIdx.x) >> 6;
    if (wave >= N_NODES) return;
    const int lane = threadIdx.x & 63;
    const int node = wave;

    union { unsigned u; float f; } cv;
    const unsigned uq = *(const unsigned*)(q + (size_t)node * HC + lane * 2);
    cv.u = uq << 16;          float qx = cv.f;
    cv.u = uq & 0xFFFF0000u;  float qy = cv.f;

    float accx = 0.f, accy = 0.f, ssum = 0.f;
    const int beg = __builtin_amdgcn_readfirstlane(rowptr[node]);
    const int end = __builtin_amdgcn_readfirstlane(rowptr[node + 1]);
    const float scale = 0.17677669529663687f;  // 1/sqrt(32)

    int e = beg;
    for (; e + 3 < end; e += 4) {
        const int j0 = ssrc[e],     j1 = ssrc[e + 1];
        const int j2 = ssrc[e + 2], j3 = ssrc[e + 3];
        const unsigned uk0 = *(const unsigned*)(k + (size_t)j0 * HC + lane * 2);
        const unsigned uk1 = *(const unsigned*)(k + (size_t)j1 * HC + lane * 2);
        const unsigned uk2 = *(const unsigned*)(k + (size_t)j2 * HC + lane * 2);
        const unsigned uk3 = *(const unsigned*)(k + (size_t)j3 * HC + lane * 2);
        const unsigned uv0 = *(const unsigned*)(v + (size_t)j0 * HC + lane * 2);
        const unsigned uv1 = *(const unsigned*)(v + (size_t)j1 * HC + lane * 2);
        const unsigned uv2 = *(const unsigned*)(v + (size_t)j2 * HC + lane * 2);
        const unsigned uv3 = *(const unsigned*)(v + (size_t)j3 * HC + lane * 2);
        float p0, p1, p2, p3;
        { float kx, ky;
          cv.u = uk0 << 16; kx = cv.f; cv.u = uk0 & 0xFFFF0000u; ky = cv.f;
          p0 = qx * kx + qy * ky;
          cv.u = uk1 << 16; kx = cv.f; cv.u = uk1 & 0xFFFF0000u; ky = cv.f;
          p1 = qx * kx + qy * ky;
          cv.u = uk2 << 16; kx = cv.f; cv.u = uk2 & 0xFFFF0000u; ky = cv.f;
          p2 = qx * kx + qy * ky;
          cv.u = uk3 << 16; kx = cv.f; cv.u = uk3 & 0xFFFF0000u; ky = cv.f;
          p3 = qx * kx + qy * ky; }
#pragma unroll
        for (int off = 1; off <= 8; off <<= 1) {
            p0 += __shfl_xor(p0, off);
            p1 += __shfl_xor(p1, off);
            p2 += __shfl_xor(p2, off);
            p3 += __shfl_xor(p3, off);
        }
        const float w0 = __expf(p0 * scale);
        const float w1 = __expf(p1 * scale);
        const float w2 = __expf(p2 * scale);
        const float w3 = __expf(p3 * scale);
        { float vx, vy;
          cv.u = uv0 << 16; vx = cv.f; cv.u = uv0 & 0xFFFF0000u; vy = cv.f;
          accx += w0 * vx; accy += w0 * vy;
          cv.u = uv1 << 16; vx = cv.f; cv.u = uv1 & 0xFFFF0000u; vy = cv.f;
          accx += w1 * vx; accy += w1 * vy;
          cv.u = uv2 << 16; vx = cv.f; cv.u = uv2 & 0xFFFF0000u; vy = cv.f;
          accx += w2 * vx; accy += w2 * vy;
          cv.u = uv3 << 16; vx = cv.f; cv.u = uv3 & 0xFFFF0000u; vy = cv.f;
          accx += w3 * vx; accy += w3 * vy; }
        ssum += (w0 + w1) + (w2 + w3);
    }
    for (; e < end; e++) {
        const int j0 = ssrc[e];
        const unsigned uk0 = *(const unsigned*)(k + (size_t)j0 * HC + lane * 2);
        const unsigned uv0 = *(const unsigned*)(v + (size_t)j0 * HC + lane * 2);
        float kx, ky;
        cv.u = uk0 << 16; kx = cv.f; cv.u = uk0 & 0xFFFF0000u; ky = cv.f;
        float p0 = qx * kx + qy * ky;
        p0 += __shfl_xor(p0, 1);
        p0 += __shfl_xor(p0, 2);
        p0 += __shfl_xor(p0, 4);
        p0 += __shfl_xor(p0, 8);
        const float w0 = __expf(p0 * scale);
        float vx, vy;
        cv.u = uv0 << 16; vx = cv.f; cv.u = uv0 & 0xFFFF0000u; vy = cv.f;
        accx += w0 * vx; accy += w0 * vy;
        ssum += w0;
    }

    const float inv = 1.0f / (ssum + 1e-16f);
    const float2 sk = *(const float2*)(out + (size_t)node * HC + lane * 2);
    float ox = accx * inv + sk.x;
    float oy = accy * inv + sk.y;
    ox = ox >= 0.f ? ox : 0.2f * ox;
    oy = oy >= 0.f ? oy : 0.2f * oy;
    *(float2*)(out + (size_t)node * HC + lane * 2) = make_float2(ox, oy);
}

// ---------------- launch ---------------------------------------------------
extern "C" void kernel_launch(void* const* d_in, const int* in_sizes, int n_in,
                              void* d_out, int out_size, void* d_ws, size_t ws_size,
                              hipStream_t stream)
{
    const float* x    = (const float*)d_in[0];
    const int*   ei   = (const int*)d_in[1];
    const float* Wq   = (const float*)d_in[2];
    const float* bq   = (const float*)d_in[3];
    const float* Wk   = (const float*)d_in[4];
    const float* bk   = (const float*)d_in[5];
    const float* Wv   = (const float*)d_in[6];
    const float* bv   = (const float*)d_in[7];
    const float* Wsk  = (const float*)d_in[8];
    const float* bsk  = (const float*)d_in[9];
    float* out = (float*)d_out;

    char* w = (char*)d_ws;
    const size_t NFB = (size_t)N_NODES * HC * sizeof(unsigned short); // 12.8MB
    unsigned short* q = (unsigned short*)w;            w += NFB;
    unsigned short* k = (unsigned short*)w;            w += NFB;
    unsigned short* v = (unsigned short*)w;            w += NFB;
    short* bpack = (short*)w;                          w += 8192 * 8 * sizeof(short);
    float* bcat  = (float*)w;                          w += NCOLS * sizeof(float);
    int* cnt    = (int*)w;                             w += N_NODES * sizeof(int);
    int* rowptr = (int*)w;                             w += (N_NODES + 1) * sizeof(int);
    int* bsum   = (int*)w;                             w += SCAN_BLOCKS * sizeof(int);
    int* boff   = (int*)w;                             w += SCAN_BLOCKS * sizeof(int);
    int* rank   = (int*)w;                             w += (size_t)E_EDGES * sizeof(int);
    int* ssrc   = (int*)w;

    const int* srcIdx = ei;
    const int* dstIdx = ei + E_EDGES;

    hipMemsetAsync(cnt, 0, N_NODES * sizeof(int), stream);

    pack_w<<<32, 256, 0, stream>>>(Wq, Wk, Wv, Wsk, bq, bk, bv, bsk, bpack, bcat);
    hist_k<<<(E_EDGES + 255) / 256, 256, 0, stream>>>(dstIdx, cnt, rank);
    gemm_mfma<<<ROWTILES, 256, 0, stream>>>(x, bpack, bcat, q, k, v, out);
    bsum_k<<<SCAN_BLOCKS, 256, 0, stream>>>(cnt, bsum);
    bscan_k<<<1, 256, 0, stream>>>(bsum, boff);
    bapply_k<<<SCAN_BLOCKS, 256, 0, stream>>>(cnt, boff, rowptr);
    scatter_k<<<(E_EDGES + 255) / 256, 256, 0, stream>>>(srcIdx, dstIdx, rowptr, rank, ssrc);
    node_attn<<<(N_NODES * 64) / 256, 256, 0, stream>>>(q, k, v, rowptr, ssrc, out);
}